// Round 1
// 411.416 us; speedup vs baseline: 1.0392x; 1.0392x over previous
//
#include <hip/hip_runtime.h>

// Problem constants
#define B_  8192
#define L_  10
#define D_  128
#define H_  64
#define OUT_ 5

typedef _Float16 h2 __attribute__((ext_vector_type(2)));
typedef _Float16 f16x8 __attribute__((ext_vector_type(8)));
typedef float f32x4 __attribute__((ext_vector_type(4)));
typedef unsigned int uint;

// ws dword layout:
#define WS_ENCPK   0        // [kp<96][l]: uint4, dword q = half2(W[q*64+l][2kp], [2kp+1]); k<128: Wih, else Whh
#define WS_ENCB    24576    // 256 floats: [l][q] = bih+bhh
#define WS_DECY    24832    // [k<5][l]: float4 fp32 (dec Wih columns)
#define WS_DECPK   26112    // [ep<32][l]: uint4, half2(decWhh[q*64+l][2ep], [2ep+1])
#define WS_DECB    34304    // 256 floats
#define WS_W1HCP   34560    // [ep<32][l]: uint2 {half2 W1h pair, half2 W1c pair}
#define WS_W1XP    38656    // [ep<32][l]: uint half2 W1x pair
#define WS_G       40960    // G'[row=(b*L+t)][j 0..255] f16, bias folded (512B/row, same footprint as before)

__device__ __forceinline__ float sigmf(float x){ return 1.f/(1.f+__expf(-x)); }
__device__ __forceinline__ float tanhf_(float x){ return 1.f - 2.f/(1.f+__expf(2.f*x)); }
__device__ __forceinline__ uint bcastu(uint v, int lane){
  return (uint)__builtin_amdgcn_readlane((int)v, lane);
}
__device__ __forceinline__ float dot2(uint w, uint a, float acc){
  return __builtin_amdgcn_fdot2(__builtin_bit_cast(h2, w), __builtin_bit_cast(h2, a), acc, false);
}
__device__ __forceinline__ uint pack_rtz(float a, float b){
  return __builtin_bit_cast(uint, __builtin_amdgcn_cvt_pkrtz(a, b));
}
__device__ __forceinline__ uint pack_rtn(float a, float b){
  h2 v; v.x = (_Float16)a; v.y = (_Float16)b;
  return __builtin_bit_cast(uint, v);
}
__device__ __forceinline__ float2 unpk(uint u){
  h2 v = __builtin_bit_cast(h2, u);
  return make_float2((float)v.x, (float)v.y);
}

__global__ void prep_kernel(const float* __restrict__ encWih, const float* __restrict__ encWhh,
                            const float* __restrict__ encbih, const float* __restrict__ encbhh,
                            const float* __restrict__ decWih, const float* __restrict__ decWhh,
                            const float* __restrict__ decbih, const float* __restrict__ decbhh,
                            const float* __restrict__ w1, float* __restrict__ wsf)
{
  uint* ws = (uint*)wsf;
  int stride = gridDim.x * blockDim.x;
  int tid0 = blockIdx.x * blockDim.x + threadIdx.x;

  for (int idx = tid0; idx < 96*64; idx += stride) {
    int kp = idx >> 6, l = idx & 63;
    uint4 o; uint* op = (uint*)&o;
    #pragma unroll
    for (int q=0;q<4;++q){
      int j = q*64 + l;
      int k0 = 2*kp, k1 = 2*kp+1;
      float a = (k0 < 128) ? encWih[j*128 + k0] : encWhh[j*64 + (k0-128)];
      float b = (k1 < 128) ? encWih[j*128 + k1] : encWhh[j*64 + (k1-128)];
      op[q] = pack_rtn(a,b);
    }
    ((uint4*)(ws + WS_ENCPK))[idx] = o;
  }
  for (int idx = tid0; idx < 256; idx += stride) {
    int l = idx >> 2, q = idx & 3, j = q*64+l;
    wsf[WS_ENCB+idx] = encbih[j] + encbhh[j];
  }
  for (int idx = tid0; idx < 5*64; idx += stride) {
    int k = idx >> 6, l = idx & 63;
    float4 o;
    o.x = decWih[(0*64+l)*5 + k];
    o.y = decWih[(1*64+l)*5 + k];
    o.z = decWih[(2*64+l)*5 + k];
    o.w = decWih[(3*64+l)*5 + k];
    ((float4*)(wsf + WS_DECY))[idx] = o;
  }
  for (int idx = tid0; idx < 32*64; idx += stride) {
    int ep = idx >> 6, l = idx & 63;
    uint4 o; uint* op = (uint*)&o;
    #pragma unroll
    for (int q=0;q<4;++q){
      int j = q*64 + l;
      op[q] = pack_rtn(decWhh[j*64 + 2*ep], decWhh[j*64 + 2*ep+1]);
    }
    ((uint4*)(ws + WS_DECPK))[idx] = o;
  }
  for (int idx = tid0; idx < 256; idx += stride) {
    int l = idx >> 2, q = idx & 3, j = q*64+l;
    wsf[WS_DECB+idx] = decbih[j] + decbhh[j];
  }
  for (int idx = tid0; idx < 32*64; idx += stride) {
    int ep = idx >> 6, l = idx & 63;
    uint2 o;
    o.x = pack_rtn(w1[l*192 + 2*ep],      w1[l*192 + 2*ep+1]);
    o.y = pack_rtn(w1[l*192 + 64 + 2*ep], w1[l*192 + 64 + 2*ep+1]);
    ((uint2*)(ws + WS_W1HCP))[idx] = o;
  }
  for (int idx = tid0; idx < 32*64; idx += stride) {
    int ep = idx >> 6, l = idx & 63;
    ws[WS_W1XP + idx] = pack_rtn(w1[l*192 + 128 + 2*ep], w1[l*192 + 128 + 2*ep+1]);
  }
}

// MFMA G-producer: G'[(b,t)][j] = ((at(b) .* x[b,t]) @ encWih^T + bias)[j], f16.
// Block = 16 batch rows, 4 independent waves (no LDS, no barriers).
// Wave w computes M-tiles mt = 4w+im (j = 64w+16im .. +15) for all 10 t:
//   A = encWih (16j x 32k per frag), gathered from existing encPk packing (64 dwords, once).
//   B = wi = at*x, built per (t,kf) from two float4 x loads (same rtz rounding as before).
//   C frag: col(l&15)=batch row, row((l>>4)*4+reg)=j -> stores land in plain j-order.
__global__ __launch_bounds__(256, 2) void gemmG_mfma(
    const float* __restrict__ x, const float* __restrict__ enc_attn_w,
    const float* __restrict__ ws, _Float16* __restrict__ Gh)
{
  const int l   = threadIdx.x & 63;
  const int w   = threadIdx.x >> 6;   // wave id 0..3 -> gate group
  const int col = l & 15;             // batch sub-row (MFMA N / B-col)
  const int g   = l >> 4;             // k-group 0..3
  const int b0  = blockIdx.x * 16;
  const uint* wsu = (const uint*)ws;

  // ---- gather A-frags (weights): afr[im][kf], j = (4w+im)*16 + col, k = kf*32 + g*8 + h
  f16x8 afr[4][4];
  #pragma unroll
  for (int im=0; im<4; ++im){
    #pragma unroll
    for (int kf=0; kf<4; ++kf){
      union { uint u[4]; f16x8 v; } cv;
      #pragma unroll
      for (int i=0;i<4;++i){
        int kp = kf*16 + g*4 + i;          // k-pair index (k = 2*kp, 2*kp+1)
        int lsrc = im*16 + col;            // j = w*64 + lsrc
        cv.u[i] = wsu[WS_ENCPK + (kp*64 + lsrc)*4 + w];
      }
      afr[im][kf] = cv.v;
    }
  }
  // ---- bias for acc rows: j = (4w+im)*16 + g*4 + r  ->  ENCB[(im*16+g*4+r)*4 + w]
  float bias[4][4];
  #pragma unroll
  for (int im=0; im<4; ++im)
    #pragma unroll
    for (int r=0; r<4; ++r)
      bias[im][r] = ws[WS_ENCB + (im*16 + g*4 + r)*4 + w];

  float wxv[L_];
  #pragma unroll
  for (int t=0;t<L_;++t) wxv[t] = enc_attn_w[2*H_ + t];

  const float* xb = x + (size_t)(b0+col)*(L_*D_);

  // ---- attention softmax over k=128 for b = b0+col (h@wh + c@wc + b cancel in softmax)
  float sc[4][8];   // [kf][h] : score, then at
  #pragma unroll
  for (int kf=0;kf<4;++kf)
    #pragma unroll
    for (int h=0;h<8;++h) sc[kf][h]=0.f;
  #pragma unroll 2
  for (int t=0;t<L_;++t){
    float wx = wxv[t];
    #pragma unroll
    for (int kf=0;kf<4;++kf){
      const float* p = xb + t*D_ + kf*32 + g*8;
      float4 x0 = *(const float4*)p, x1 = *(const float4*)(p+4);
      sc[kf][0]+=x0.x*wx; sc[kf][1]+=x0.y*wx; sc[kf][2]+=x0.z*wx; sc[kf][3]+=x0.w*wx;
      sc[kf][4]+=x1.x*wx; sc[kf][5]+=x1.y*wx; sc[kf][6]+=x1.z*wx; sc[kf][7]+=x1.w*wx;
    }
  }
  float m = sc[0][0];
  #pragma unroll
  for (int kf=0;kf<4;++kf)
    #pragma unroll
    for (int h=0;h<8;++h) m = fmaxf(m, sc[kf][h]);
  m = fmaxf(m, __shfl_xor(m,16));
  m = fmaxf(m, __shfl_xor(m,32));
  float ss = 0.f;
  #pragma unroll
  for (int kf=0;kf<4;++kf)
    #pragma unroll
    for (int h=0;h<8;++h){ sc[kf][h] = __expf(sc[kf][h]-m); ss += sc[kf][h]; }
  ss += __shfl_xor(ss,16);
  ss += __shfl_xor(ss,32);
  float inv = 1.f/ss;
  #pragma unroll
  for (int kf=0;kf<4;++kf)
    #pragma unroll
    for (int h=0;h<8;++h) sc[kf][h] *= inv;

  // ---- main loop: per t, build wi B-frags, 16 MFMA, store 4x uint2 (j-ordered f16)
  #pragma unroll 2
  for (int t=0;t<L_;++t){
    f16x8 bfr[4];
    #pragma unroll
    for (int kf=0;kf<4;++kf){
      const float* p = xb + t*D_ + kf*32 + g*8;
      float4 x0 = *(const float4*)p, x1 = *(const float4*)(p+4);
      union { uint u[4]; f16x8 v; } cv;
      cv.u[0] = pack_rtz(sc[kf][0]*x0.x, sc[kf][1]*x0.y);
      cv.u[1] = pack_rtz(sc[kf][2]*x0.z, sc[kf][3]*x0.w);
      cv.u[2] = pack_rtz(sc[kf][4]*x1.x, sc[kf][5]*x1.y);
      cv.u[3] = pack_rtz(sc[kf][6]*x1.z, sc[kf][7]*x1.w);
      bfr[kf] = cv.v;
    }
    _Float16* grow = Gh + ((size_t)(b0+col)*L_ + t)*256;
    #pragma unroll
    for (int im=0;im<4;++im){
      f32x4 acc = { bias[im][0], bias[im][1], bias[im][2], bias[im][3] };
      #pragma unroll
      for (int kf=0;kf<4;++kf)
        acc = __builtin_amdgcn_mfma_f32_16x16x32_f16(afr[im][kf], bfr[kf], acc, 0, 0, 0);
      uint2 o = make_uint2(pack_rtn(acc[0],acc[1]), pack_rtn(acc[2],acc[3]));
      *(uint2*)(grow + (4*w+im)*16 + g*4) = o;
    }
  }
}

#define R 2   // batch rows per wave (grid = 1024 blocks)

__global__ __launch_bounds__(256, 2) void darnn_kernel(
    const float* __restrict__ y_hist,
    const float* __restrict__ h0e, const float* __restrict__ c0e,
    const float* __restrict__ h0d, const float* __restrict__ c0d,
    const float* __restrict__ dec_attn_b1, const float* __restrict__ dec_attn_w2,
    const float* __restrict__ fc_w, const float* __restrict__ fc_b,
    const float* __restrict__ fcout_w, const float* __restrict__ fcout_b,
    const float* __restrict__ ws, const uint2* __restrict__ Gp,
    float* __restrict__ out)
{
  const int l  = threadIdx.x & 63;
  const int wv = threadIdx.x >> 6;
  const int brow = blockIdx.x * (4*R) + wv*R;
  const int m2 = 2*(l&31);

  const uint4*  encPk = (const uint4*)((const uint*)ws + WS_ENCPK);
  const float4* decY  = (const float4*)(ws + WS_DECY);
  const uint4*  decPk = (const uint4*)((const uint*)ws + WS_DECPK);
  const uint2*  w1hcp = (const uint2*)((const uint*)ws + WS_W1HCP);
  const uint*   w1xp  = (const uint*)ws + WS_W1XP;
  const _Float16* Gh  = (const _Float16*)Gp;

  float h[R], c[R];
  #pragma unroll
  for (int r=0;r<R;++r){
    h[r]=h0e[(brow+r)*64+l];
    c[r]=c0e[(brow+r)*64+l];
  }

  float xe[R][L_];

  // -------- Encoder: recurrent part only (input gates precomputed in G') --------
  {
    float gnx[R][4];
    #pragma unroll
    for (int r=0;r<R;++r){
      const _Float16* gb = Gh + ((size_t)(brow+r)*L_)*256 + l;
      gnx[r][0]=(float)gb[0];   gnx[r][1]=(float)gb[64];
      gnx[r][2]=(float)gb[128]; gnx[r][3]=(float)gb[192];
    }
    for (int t=0;t<L_;++t){
      float a0[R]={gnx[0][0],gnx[1][0]}, a1[R]={gnx[0][1],gnx[1][1]};
      float a2[R]={gnx[0][2],gnx[1][2]}, a3[R]={gnx[0][3],gnx[1][3]};
      if (t+1<L_){
        #pragma unroll
        for (int r=0;r<R;++r){
          const _Float16* gb = Gh + ((size_t)(brow+r)*L_+(t+1))*256 + l;
          gnx[r][0]=(float)gb[0];   gnx[r][1]=(float)gb[64];
          gnx[r][2]=(float)gb[128]; gnx[r][3]=(float)gb[192];
        }
      }
      uint hp[R];
      #pragma unroll
      for (int r=0;r<R;++r)
        hp[r]=pack_rtz(__shfl(h[r],m2), __shfl(h[r],m2+1));
      #pragma unroll 4
      for (int kp=0; kp<32; ++kp){
        uint4 w = encPk[(64+kp)*64+l];
        #pragma unroll
        for (int r=0;r<R;++r){
          uint u = bcastu(hp[r], kp);
          a0[r]=dot2(w.x,u,a0[r]); a1[r]=dot2(w.y,u,a1[r]);
          a2[r]=dot2(w.z,u,a2[r]); a3[r]=dot2(w.w,u,a3[r]);
        }
      }
      #pragma unroll
      for (int r=0;r<R;++r){
        float ig=sigmf(a0[r]), fg=sigmf(a1[r]), gg=tanhf_(a2[r]), og=sigmf(a3[r]);
        c[r]=fg*c[r]+ig*gg;
        h[r]=og*tanhf_(c[r]);
        xe[r][t]=h[r];
      }
    }
  }

  // pre[r][lt] = sum_e xe[r][lt](e) * W1x[l][e]  via packed pairs
  float pre[R][L_];
  {
    uint xep[R][L_];
    #pragma unroll
    for (int r=0;r<R;++r)
      #pragma unroll
      for (int lt=0;lt<L_;++lt){
        xep[r][lt]=pack_rtz(__shfl(xe[r][lt],m2), __shfl(xe[r][lt],m2+1));
        pre[r][lt]=0.f;
      }
    #pragma unroll 2
    for (int ep=0;ep<32;++ep){
      uint w = w1xp[ep*64+l];
      #pragma unroll
      for (int r=0;r<R;++r)
        #pragma unroll
        for (int lt=0;lt<L_;++lt)
          pre[r][lt] = dot2(w, bcastu(xep[r][lt], ep), pre[r][lt]);
    }
  }

  // ---------------- Decoder ----------------
  #pragma unroll
  for (int r=0;r<R;++r){
    h[r]=h0d[(brow+r)*64+l];
    c[r]=c0d[(brow+r)*64+l];
  }
  float b1l = dec_attn_b1[l];
  float w2l = dec_attn_w2[l];
  float ctx[R];
  #pragma unroll
  for (int r=0;r<R;++r) ctx[r]=0.f;

  const float* yb0 = y_hist + (size_t)(brow+0)*(L_*OUT_);
  const float* yb1 = y_hist + (size_t)(brow+1)*(L_*OUT_);

  for (int t=0;t<L_;++t){
    uint hp[R], cp[R];
    #pragma unroll
    for (int r=0;r<R;++r){
      hp[r]=pack_rtz(__shfl(h[r],m2), __shfl(h[r],m2+1));
      cp[r]=pack_rtz(__shfl(c[r],m2), __shfl(c[r],m2+1));
    }
    // vb[l] = b1[l] + sum_e h(e)W1h[l][e] + c(e)W1c[l][e]
    float vb[R];
    #pragma unroll
    for (int r=0;r<R;++r) vb[r]=b1l;
    #pragma unroll 4
    for (int ep=0;ep<32;++ep){
      uint2 w = w1hcp[ep*64+l];
      #pragma unroll
      for (int r=0;r<R;++r){
        vb[r]=dot2(w.x, bcastu(hp[r],ep), vb[r]);
        vb[r]=dot2(w.y, bcastu(cp[r],ep), vb[r]);
      }
    }
    // scores -> softmax over L -> ctx
    float yt[R][OUT_];
    #pragma unroll
    for (int r=0;r<R;++r){
      float sc[L_];
      #pragma unroll
      for (int lt=0;lt<L_;++lt){
        float z = tanhf_(pre[r][lt]+vb[r]);
        float p = z*w2l;
        for (int o=32;o;o>>=1) p += __shfl_xor(p,o);
        sc[lt]=p;
      }
      float mx=sc[0];
      #pragma unroll
      for (int lt=1;lt<L_;++lt) mx=fmaxf(mx,sc[lt]);
      float ssum=0.f;
      #pragma unroll
      for (int lt=0;lt<L_;++lt){ sc[lt]=__expf(sc[lt]-mx); ssum+=sc[lt]; }
      float inv=1.f/ssum;
      float cx=0.f;
      #pragma unroll
      for (int lt=0;lt<L_;++lt) cx += sc[lt]*xe[r][lt];
      ctx[r]=cx*inv;
    }
    // y_tilde
    #pragma unroll
    for (int r=0;r<R;++r){
      const float* yb = (r==0)?yb0:yb1;
      float yin[OUT_];
      #pragma unroll
      for (int j=0;j<OUT_;++j) yin[j]=yb[t*OUT_+j];
      #pragma unroll
      for (int o2=0;o2<OUT_;++o2){
        float p = ctx[r]*fc_w[o2*69+l];
        for (int o=32;o;o>>=1) p += __shfl_xor(p,o);
        p += fc_b[o2];
        #pragma unroll
        for (int j=0;j<OUT_;++j) p += yin[j]*fc_w[o2*69+64+j];
        yt[r][o2]=p;
      }
    }
    // gates
    float4 bs = *(const float4*)(ws + WS_DECB + l*4);
    float a0[R],a1[R],a2[R],a3[R];
    #pragma unroll
    for (int r=0;r<R;++r){ a0[r]=bs.x;a1[r]=bs.y;a2[r]=bs.z;a3[r]=bs.w; }
    #pragma unroll
    for (int k=0;k<OUT_;++k){
      float4 w = decY[k*64+l];
      #pragma unroll
      for (int r=0;r<R;++r){
        float v = yt[r][k];
        a0[r]+=v*w.x;a1[r]+=v*w.y;a2[r]+=v*w.z;a3[r]+=v*w.w;
      }
    }
    #pragma unroll 4
    for (int ep=0;ep<32;++ep){
      uint4 w = decPk[ep*64+l];
      #pragma unroll
      for (int r=0;r<R;++r){
        uint u = bcastu(hp[r], ep);
        a0[r]=dot2(w.x,u,a0[r]); a1[r]=dot2(w.y,u,a1[r]);
        a2[r]=dot2(w.z,u,a2[r]); a3[r]=dot2(w.w,u,a3[r]);
      }
    }
    #pragma unroll
    for (int r=0;r<R;++r){
      float ig=sigmf(a0[r]), fg=sigmf(a1[r]), gg=tanhf_(a2[r]), og=sigmf(a3[r]);
      c[r]=fg*c[r]+ig*gg;
      h[r]=og*tanhf_(c[r]);
    }
  }

  // out epilogue
  #pragma unroll
  for (int o2=0;o2<OUT_;++o2){
    float wa=fcout_w[o2*128+l];
    float wb=fcout_w[o2*128+64+l];
    float fb=fcout_b[o2];
    #pragma unroll
    for (int r=0;r<R;++r){
      float p = h[r]*wa + ctx[r]*wb;
      for (int o=32;o;o>>=1) p += __shfl_xor(p,o);
      if (l==o2) out[(size_t)(brow+r)*OUT_+o2] = p+fb;
    }
  }
}

extern "C" void kernel_launch(void* const* d_in, const int* in_sizes, int n_in,
                              void* d_out, int out_size, void* d_ws, size_t ws_size,
                              hipStream_t stream) {
  const float* x          = (const float*)d_in[0];
  const float* y_hist     = (const float*)d_in[1];
  const float* h0_enc     = (const float*)d_in[2];
  const float* c0_enc     = (const float*)d_in[3];
  const float* h0_dec     = (const float*)d_in[4];
  const float* c0_dec     = (const float*)d_in[5];
  const float* enc_attn_w = (const float*)d_in[6];
  const float* enc_Wih    = (const float*)d_in[8];
  const float* enc_Whh    = (const float*)d_in[9];
  const float* enc_bih    = (const float*)d_in[10];
  const float* enc_bhh    = (const float*)d_in[11];
  const float* dec_attn_w1= (const float*)d_in[12];
  const float* dec_attn_b1= (const float*)d_in[13];
  const float* dec_attn_w2= (const float*)d_in[14];
  const float* dec_Wih    = (const float*)d_in[16];
  const float* dec_Whh    = (const float*)d_in[17];
  const float* dec_bih    = (const float*)d_in[18];
  const float* dec_bhh    = (const float*)d_in[19];
  const float* fc_w       = (const float*)d_in[20];
  const float* fc_b       = (const float*)d_in[21];
  const float* fcout_w    = (const float*)d_in[22];
  const float* fcout_b    = (const float*)d_in[23];
  float* ws = (float*)d_ws;
  float* out = (float*)d_out;
  uint2* Gp = (uint2*)((uint*)d_ws + WS_G);

  hipLaunchKernelGGL(prep_kernel, dim3(128), dim3(256), 0, stream,
                     enc_Wih, enc_Whh, enc_bih, enc_bhh,
                     dec_Wih, dec_Whh, dec_bih, dec_bhh,
                     dec_attn_w1, ws);
  hipLaunchKernelGGL(gemmG_mfma, dim3(B_/16), dim3(256), 0, stream,
                     x, enc_attn_w, ws, (_Float16*)Gp);
  hipLaunchKernelGGL(darnn_kernel, dim3(B_/(4*R)), dim3(256), 0, stream,
                     y_hist, h0_enc, c0_enc, h0_dec, c0_dec,
                     dec_attn_b1, dec_attn_w2,
                     fc_w, fc_b, fcout_w, fcout_b, ws, Gp, out);
}

// Round 2
// 275.407 us; speedup vs baseline: 1.5524x; 1.4938x over previous
//
#include <hip/hip_runtime.h>

// Problem constants
#define B_  8192
#define L_  10
#define D_  128
#define H_  64
#define OUT_ 5

typedef _Float16 h2 __attribute__((ext_vector_type(2)));
typedef _Float16 f16x8 __attribute__((ext_vector_type(8)));
typedef float f32x4 __attribute__((ext_vector_type(4)));
typedef unsigned int uint;

// ws dword layout:
#define WS_ENCPK   0        // [kp<96][l]: uint4, dword q = half2(W[q*64+l][2kp], [2kp+1]); k<128: Wih, else Whh
#define WS_ENCB    24576    // 256 floats: [l][q] = bih+bhh
#define WS_DECY2   24832    // [i<4][l<64]: uint4, comp q = half2(decWih[q*64+l][2i], [2i+1]) zero-padded k>=5
#define WS_DECPK   26112    // [ep<32][l]: uint4, half2(decWhh[q*64+l][2ep], [2ep+1])
#define WS_DECB    34304    // 256 floats: [u][q]
#define WS_W1HCP   34560    // [ep<32][l]: uint2 {half2 W1h pair, half2 W1c pair}
#define WS_W1XP    38656    // [ep<32][l]: uint half2 W1x pair
#define WS_G       40960    // G'[row=(b*L+t)][j 0..255] f16, bias folded (512B/row)

__device__ __forceinline__ float sigmf(float x){ return 1.f/(1.f+__expf(-x)); }
__device__ __forceinline__ float tanhf_(float x){ return 1.f - 2.f/(1.f+__expf(2.f*x)); }
__device__ __forceinline__ uint pack_rtz(float a, float b){
  return __builtin_bit_cast(uint, __builtin_amdgcn_cvt_pkrtz(a, b));
}
__device__ __forceinline__ uint pack_rtn(float a, float b){
  h2 v; v.x = (_Float16)a; v.y = (_Float16)b;
  return __builtin_bit_cast(uint, v);
}
__device__ __forceinline__ float2 unpk(uint u){
  h2 v = __builtin_bit_cast(h2, u);
  return make_float2((float)v.x, (float)v.y);
}

union U4 { uint u[4]; uint4 q; f16x8 v; };

__global__ void prep_kernel(const float* __restrict__ encWih, const float* __restrict__ encWhh,
                            const float* __restrict__ encbih, const float* __restrict__ encbhh,
                            const float* __restrict__ decWih, const float* __restrict__ decWhh,
                            const float* __restrict__ decbih, const float* __restrict__ decbhh,
                            const float* __restrict__ w1, float* __restrict__ wsf)
{
  uint* ws = (uint*)wsf;
  int stride = gridDim.x * blockDim.x;
  int tid0 = blockIdx.x * blockDim.x + threadIdx.x;

  for (int idx = tid0; idx < 96*64; idx += stride) {
    int kp = idx >> 6, l = idx & 63;
    uint4 o; uint* op = (uint*)&o;
    #pragma unroll
    for (int q=0;q<4;++q){
      int j = q*64 + l;
      int k0 = 2*kp, k1 = 2*kp+1;
      float a = (k0 < 128) ? encWih[j*128 + k0] : encWhh[j*64 + (k0-128)];
      float b = (k1 < 128) ? encWih[j*128 + k1] : encWhh[j*64 + (k1-128)];
      op[q] = pack_rtn(a,b);
    }
    ((uint4*)(ws + WS_ENCPK))[idx] = o;
  }
  for (int idx = tid0; idx < 256; idx += stride) {
    int l = idx >> 2, q = idx & 3, j = q*64+l;
    wsf[WS_ENCB+idx] = encbih[j] + encbhh[j];
  }
  // dec Wih packed for MFMA kf0 (k = 0..4, zero-padded to 8)
  for (int idx = tid0; idx < 4*64; idx += stride) {
    int i = idx >> 6, l = idx & 63;
    uint4 o; uint* op = (uint*)&o;
    #pragma unroll
    for (int q=0;q<4;++q){
      int j = q*64 + l;
      int k0 = 2*i, k1 = 2*i+1;
      float a = (k0 < 5) ? decWih[j*5 + k0] : 0.f;
      float b = (k1 < 5) ? decWih[j*5 + k1] : 0.f;
      op[q] = pack_rtn(a,b);
    }
    ((uint4*)(ws + WS_DECY2))[idx] = o;
  }
  for (int idx = tid0; idx < 32*64; idx += stride) {
    int ep = idx >> 6, l = idx & 63;
    uint4 o; uint* op = (uint*)&o;
    #pragma unroll
    for (int q=0;q<4;++q){
      int j = q*64 + l;
      op[q] = pack_rtn(decWhh[j*64 + 2*ep], decWhh[j*64 + 2*ep+1]);
    }
    ((uint4*)(ws + WS_DECPK))[idx] = o;
  }
  for (int idx = tid0; idx < 256; idx += stride) {
    int l = idx >> 2, q = idx & 3, j = q*64+l;
    wsf[WS_DECB+idx] = decbih[j] + decbhh[j];
  }
  for (int idx = tid0; idx < 32*64; idx += stride) {
    int ep = idx >> 6, l = idx & 63;
    uint2 o;
    o.x = pack_rtn(w1[l*192 + 2*ep],      w1[l*192 + 2*ep+1]);
    o.y = pack_rtn(w1[l*192 + 64 + 2*ep], w1[l*192 + 64 + 2*ep+1]);
    ((uint2*)(ws + WS_W1HCP))[idx] = o;
  }
  for (int idx = tid0; idx < 32*64; idx += stride) {
    int ep = idx >> 6, l = idx & 63;
    ws[WS_W1XP + idx] = pack_rtn(w1[l*192 + 128 + 2*ep], w1[l*192 + 128 + 2*ep+1]);
  }
}

// MFMA G-producer (unchanged from R1 — verified): G'[(b,t)][j] f16, bias folded.
__global__ __launch_bounds__(256, 2) void gemmG_mfma(
    const float* __restrict__ x, const float* __restrict__ enc_attn_w,
    const float* __restrict__ ws, _Float16* __restrict__ Gh)
{
  const int l   = threadIdx.x & 63;
  const int w   = threadIdx.x >> 6;
  const int col = l & 15;
  const int g   = l >> 4;
  const int b0  = blockIdx.x * 16;
  const uint* wsu = (const uint*)ws;

  f16x8 afr[4][4];
  #pragma unroll
  for (int im=0; im<4; ++im){
    #pragma unroll
    for (int kf=0; kf<4; ++kf){
      U4 cv;
      #pragma unroll
      for (int i=0;i<4;++i){
        int kp = kf*16 + g*4 + i;
        int lsrc = im*16 + col;
        cv.u[i] = wsu[WS_ENCPK + (kp*64 + lsrc)*4 + w];
      }
      afr[im][kf] = cv.v;
    }
  }
  float bias[4][4];
  #pragma unroll
  for (int im=0; im<4; ++im)
    #pragma unroll
    for (int r=0; r<4; ++r)
      bias[im][r] = ws[WS_ENCB + (im*16 + g*4 + r)*4 + w];

  float wxv[L_];
  #pragma unroll
  for (int t=0;t<L_;++t) wxv[t] = enc_attn_w[2*H_ + t];

  const float* xb = x + (size_t)(b0+col)*(L_*D_);

  float sc[4][8];
  #pragma unroll
  for (int kf=0;kf<4;++kf)
    #pragma unroll
    for (int hh=0;hh<8;++hh) sc[kf][hh]=0.f;
  #pragma unroll 2
  for (int t=0;t<L_;++t){
    float wx = wxv[t];
    #pragma unroll
    for (int kf=0;kf<4;++kf){
      const float* p = xb + t*D_ + kf*32 + g*8;
      float4 x0 = *(const float4*)p, x1 = *(const float4*)(p+4);
      sc[kf][0]+=x0.x*wx; sc[kf][1]+=x0.y*wx; sc[kf][2]+=x0.z*wx; sc[kf][3]+=x0.w*wx;
      sc[kf][4]+=x1.x*wx; sc[kf][5]+=x1.y*wx; sc[kf][6]+=x1.z*wx; sc[kf][7]+=x1.w*wx;
    }
  }
  float m = sc[0][0];
  #pragma unroll
  for (int kf=0;kf<4;++kf)
    #pragma unroll
    for (int hh=0;hh<8;++hh) m = fmaxf(m, sc[kf][hh]);
  m = fmaxf(m, __shfl_xor(m,16));
  m = fmaxf(m, __shfl_xor(m,32));
  float ss = 0.f;
  #pragma unroll
  for (int kf=0;kf<4;++kf)
    #pragma unroll
    for (int hh=0;hh<8;++hh){ sc[kf][hh] = __expf(sc[kf][hh]-m); ss += sc[kf][hh]; }
  ss += __shfl_xor(ss,16);
  ss += __shfl_xor(ss,32);
  float inv = 1.f/ss;
  #pragma unroll
  for (int kf=0;kf<4;++kf)
    #pragma unroll
    for (int hh=0;hh<8;++hh) sc[kf][hh] *= inv;

  #pragma unroll 2
  for (int t=0;t<L_;++t){
    f16x8 bfr[4];
    #pragma unroll
    for (int kf=0;kf<4;++kf){
      const float* p = xb + t*D_ + kf*32 + g*8;
      float4 x0 = *(const float4*)p, x1 = *(const float4*)(p+4);
      U4 cv;
      cv.u[0] = pack_rtz(sc[kf][0]*x0.x, sc[kf][1]*x0.y);
      cv.u[1] = pack_rtz(sc[kf][2]*x0.z, sc[kf][3]*x0.w);
      cv.u[2] = pack_rtz(sc[kf][4]*x1.x, sc[kf][5]*x1.y);
      cv.u[3] = pack_rtz(sc[kf][6]*x1.z, sc[kf][7]*x1.w);
      bfr[kf] = cv.v;
    }
    _Float16* grow = Gh + ((size_t)(b0+col)*L_ + t)*256;
    #pragma unroll
    for (int im=0;im<4;++im){
      f32x4 acc = { bias[im][0], bias[im][1], bias[im][2], bias[im][3] };
      #pragma unroll
      for (int kf=0;kf<4;++kf)
        acc = __builtin_amdgcn_mfma_f32_16x16x32_f16(afr[im][kf], bfr[kf], acc, 0, 0, 0);
      uint2 o = make_uint2(pack_rtn(acc[0],acc[1]), pack_rtn(acc[2],acc[3]));
      *(uint2*)(grow + (4*w+im)*16 + g*4) = o;
    }
  }
}

// Cooperative darnn: block = 4 waves, 16 batch rows. Wave w owns u-slice [16w,16w+16).
// All matmuls (enc gates, pre, dec vb, dec gates) are 16x16x32 f16 MFMA.
// h/c exchanged via double-buffered LDS; scores/y_tilde reduced via LDS partials.
__global__ __launch_bounds__(256, 2) void darnn_kernel(
    const float* __restrict__ y_hist,
    const float* __restrict__ h0e, const float* __restrict__ c0e,
    const float* __restrict__ h0d, const float* __restrict__ c0d,
    const float* __restrict__ dec_attn_b1, const float* __restrict__ dec_attn_w2,
    const float* __restrict__ fc_w, const float* __restrict__ fc_b,
    const float* __restrict__ fcout_w, const float* __restrict__ fcout_b,
    const float* __restrict__ ws, const uint2* __restrict__ Gp,
    float* __restrict__ out)
{
  const int l   = threadIdx.x & 63;
  const int w   = threadIdx.x >> 6;
  const int col = l & 15;          // batch sub-row (MFMA col) / A-row within tile
  const int g   = l >> 4;          // k-group
  const int b0  = blockIdx.x * 16;
  const int lw  = 16*w + col;      // row index into 64-wide weight tables for this wave's tile
  const int u0  = 16*w + 4*g;      // first hidden-unit of this lane's C-slice

  const uint* wsu = (const uint*)ws;
  const _Float16* Gh = (const _Float16*)Gp;

  __shared__ uint hxE[2][16][36];        // enc h, h2-packed, padded rows
  __shared__ uint hxD[2][16][36];        // dec h
  __shared__ uint cxD[2][16][36];        // dec c
  __shared__ _Float16 xeS[L_][16][72];   // enc outputs (f16) for pre-phase B-frags
  __shared__ float sred[L_][16][4];      // score partials [lt][b][w]
  __shared__ float yred[OUT_][16][4];    // y_tilde partials [o2][b][w]

  // ---------------- hoisted weight fragments ----------------
  f16x8 aE[4][2];   // enc Whh: mt=4q+w, kf<2
  #pragma unroll
  for (int q=0;q<4;++q)
    #pragma unroll
    for (int kf=0;kf<2;++kf){
      U4 cv;
      #pragma unroll
      for (int i=0;i<4;++i)
        cv.u[i] = wsu[WS_ENCPK + ((64 + kf*16 + g*4 + i)*64 + lw)*4 + q];
      aE[q][kf] = cv.v;
    }

  // ---------------- encoder ----------------
  float h[4], c[4], xer[L_][4];
  {
    float4 hv = *(const float4*)(h0e + (size_t)(b0+col)*64 + u0);
    float4 cv = *(const float4*)(c0e + (size_t)(b0+col)*64 + u0);
    h[0]=hv.x; h[1]=hv.y; h[2]=hv.z; h[3]=hv.w;
    c[0]=cv.x; c[1]=cv.y; c[2]=cv.z; c[3]=cv.w;
  }
  *(uint2*)&hxE[0][col][u0>>1] = make_uint2(pack_rtz(h[0],h[1]), pack_rtz(h[2],h[3]));
  __syncthreads();

  int p = 0;
  for (int t=0; t<L_; ++t){
    const _Float16* grow = Gh + ((size_t)(b0+col)*L_ + t)*256;
    uint2 gq[4];
    #pragma unroll
    for (int q=0;q<4;++q) gq[q] = *(const uint2*)(grow + q*64 + u0);

    f16x8 hB[2];
    { U4 t0; t0.q = *(const uint4*)&hxE[p][col][g*4];      hB[0]=t0.v; }
    { U4 t1; t1.q = *(const uint4*)&hxE[p][col][16 + g*4]; hB[1]=t1.v; }

    f32x4 acc[4];
    #pragma unroll
    for (int q=0;q<4;++q){
      float2 u0f = unpk(gq[q].x), u1f = unpk(gq[q].y);
      acc[q][0]=u0f.x; acc[q][1]=u0f.y; acc[q][2]=u1f.x; acc[q][3]=u1f.y;
    }
    #pragma unroll
    for (int q=0;q<4;++q){
      acc[q] = __builtin_amdgcn_mfma_f32_16x16x32_f16(aE[q][0], hB[0], acc[q], 0,0,0);
      acc[q] = __builtin_amdgcn_mfma_f32_16x16x32_f16(aE[q][1], hB[1], acc[q], 0,0,0);
    }
    #pragma unroll
    for (int r=0;r<4;++r){
      float ig=sigmf(acc[0][r]), fg=sigmf(acc[1][r]), gg=tanhf_(acc[2][r]), og=sigmf(acc[3][r]);
      c[r]=fg*c[r]+ig*gg;
      h[r]=og*tanhf_(c[r]);
      xer[t][r]=h[r];
    }
    uint2 hpk = make_uint2(pack_rtz(h[0],h[1]), pack_rtz(h[2],h[3]));
    *(uint2*)&xeS[t][col][u0] = hpk;
    *(uint2*)&hxE[p^1][col][u0>>1] = hpk;
    __syncthreads();
    p ^= 1;
  }

  // ---------------- pre[l, lt, b] = xe @ W1x^T ----------------
  f16x8 aX[2];
  #pragma unroll
  for (int kf=0;kf<2;++kf){
    U4 cv;
    #pragma unroll
    for (int i=0;i<4;++i) cv.u[i] = wsu[WS_W1XP + (kf*16 + g*4 + i)*64 + lw];
    aX[kf] = cv.v;
  }
  f32x4 preC[L_];
  #pragma unroll
  for (int lt=0;lt<L_;++lt){
    f32x4 a = {0.f,0.f,0.f,0.f};
    U4 bu0, bu1;
    bu0.q = *(const uint4*)&xeS[lt][col][g*8];
    bu1.q = *(const uint4*)&xeS[lt][col][32 + g*8];
    a = __builtin_amdgcn_mfma_f32_16x16x32_f16(aX[0], bu0.v, a, 0,0,0);
    a = __builtin_amdgcn_mfma_f32_16x16x32_f16(aX[1], bu1.v, a, 0,0,0);
    preC[lt] = a;
  }

  // ---------------- decoder hoists ----------------
  f16x8 aW1[4];   // K=128: kf0,1 = W1h; kf2,3 = W1c
  #pragma unroll
  for (int kf=0;kf<4;++kf){
    U4 cv;
    #pragma unroll
    for (int i=0;i<4;++i){
      int ep = (kf&1)*16 + g*4 + i;
      cv.u[i] = wsu[WS_W1HCP + (ep*64 + lw)*2 + (kf>>1)];
    }
    aW1[kf] = cv.v;
  }
  f16x8 aGh[4][2];   // dec Whh
  #pragma unroll
  for (int q=0;q<4;++q)
    #pragma unroll
    for (int kf=0;kf<2;++kf){
      U4 cv;
      #pragma unroll
      for (int i=0;i<4;++i)
        cv.u[i] = wsu[WS_DECPK + ((kf*16 + g*4 + i)*64 + lw)*4 + q];
      aGh[q][kf] = cv.v;
    }
  f16x8 aG0[4];      // dec Wih (k<5, zero-padded); nonzero only for g==0 rows of k
  #pragma unroll
  for (int q=0;q<4;++q){
    U4 cv;
    #pragma unroll
    for (int i=0;i<4;++i)
      cv.u[i] = (g==0) ? wsu[WS_DECY2 + (i*64 + lw)*4 + q] : 0u;
    aG0[q] = cv.v;
  }
  float4 bD[4];
  #pragma unroll
  for (int r=0;r<4;++r) bD[r] = *(const float4*)(ws + WS_DECB + (u0+r)*4);
  float4 b1v = *(const float4*)(dec_attn_b1 + u0);
  float4 w2v = *(const float4*)(dec_attn_w2 + u0);
  float fw1[OUT_][4];
  #pragma unroll
  for (int o2=0;o2<OUT_;++o2)
    #pragma unroll
    for (int r=0;r<4;++r) fw1[o2][r] = fc_w[o2*69 + u0 + r];

  // ---------------- decoder ----------------
  {
    float4 hv = *(const float4*)(h0d + (size_t)(b0+col)*64 + u0);
    float4 cv = *(const float4*)(c0d + (size_t)(b0+col)*64 + u0);
    h[0]=hv.x; h[1]=hv.y; h[2]=hv.z; h[3]=hv.w;
    c[0]=cv.x; c[1]=cv.y; c[2]=cv.z; c[3]=cv.w;
  }
  *(uint2*)&hxD[0][col][u0>>1] = make_uint2(pack_rtz(h[0],h[1]), pack_rtz(h[2],h[3]));
  *(uint2*)&cxD[0][col][u0>>1] = make_uint2(pack_rtz(c[0],c[1]), pack_rtz(c[2],c[3]));
  float ctx[4] = {0.f,0.f,0.f,0.f};
  __syncthreads();

  p = 0;
  for (int t=0; t<L_; ++t){
    f16x8 hB[2], cB[2];
    { U4 t0; t0.q = *(const uint4*)&hxD[p][col][g*4];      hB[0]=t0.v; }
    { U4 t1; t1.q = *(const uint4*)&hxD[p][col][16 + g*4]; hB[1]=t1.v; }
    { U4 t2; t2.q = *(const uint4*)&cxD[p][col][g*4];      cB[0]=t2.v; }
    { U4 t3; t3.q = *(const uint4*)&cxD[p][col][16 + g*4]; cB[1]=t3.v; }

    // vb[l,b] = b1 + h@W1h^T + c@W1c^T
    f32x4 vb = { b1v.x, b1v.y, b1v.z, b1v.w };
    vb = __builtin_amdgcn_mfma_f32_16x16x32_f16(aW1[0], hB[0], vb, 0,0,0);
    vb = __builtin_amdgcn_mfma_f32_16x16x32_f16(aW1[1], hB[1], vb, 0,0,0);
    vb = __builtin_amdgcn_mfma_f32_16x16x32_f16(aW1[2], cB[0], vb, 0,0,0);
    vb = __builtin_amdgcn_mfma_f32_16x16x32_f16(aW1[3], cB[1], vb, 0,0,0);

    // scores: wave-partial over this wave's 16 l's
    float at[L_];
    #pragma unroll
    for (int lt=0;lt<L_;++lt){
      float zp = 0.f;
      #pragma unroll
      for (int r=0;r<4;++r)
        zp += tanhf_(preC[lt][r] + vb[r]) * ((const float*)&w2v)[r];
      zp += __shfl_xor(zp,16);
      zp += __shfl_xor(zp,32);
      at[lt] = zp;
    }
    if (g==0){
      #pragma unroll
      for (int lt=0;lt<L_;++lt) sred[lt][col][w] = at[lt];
    }
    __syncthreads();
    #pragma unroll
    for (int lt=0;lt<L_;++lt){
      float4 s4 = *(const float4*)&sred[lt][col][0];
      at[lt] = s4.x + s4.y + s4.z + s4.w;
    }
    // softmax over L
    float mx = at[0];
    #pragma unroll
    for (int lt=1;lt<L_;++lt) mx = fmaxf(mx, at[lt]);
    float ssum = 0.f;
    #pragma unroll
    for (int lt=0;lt<L_;++lt){ at[lt] = __expf(at[lt]-mx); ssum += at[lt]; }
    float inv = 1.f/ssum;
    // ctx (f32, exact xe)
    #pragma unroll
    for (int r=0;r<4;++r){
      float cx = 0.f;
      #pragma unroll
      for (int lt=0;lt<L_;++lt) cx += at[lt]*xer[lt][r];
      ctx[r] = cx*inv;
    }
    // y_tilde partials (ctx part)
    float yp[OUT_];
    #pragma unroll
    for (int o2=0;o2<OUT_;++o2){
      float v = 0.f;
      #pragma unroll
      for (int r=0;r<4;++r) v += ctx[r]*fw1[o2][r];
      v += __shfl_xor(v,16);
      v += __shfl_xor(v,32);
      yp[o2] = v;
    }
    if (g==0){
      #pragma unroll
      for (int o2=0;o2<OUT_;++o2) yred[o2][col][w] = yp[o2];
    }
    __syncthreads();
    // finish y_tilde, pack B-frag (k=0..4 live on g==0 lanes)
    U4 ycv; ycv.u[0]=0u; ycv.u[1]=0u; ycv.u[2]=0u; ycv.u[3]=0u;
    if (g==0){
      const float* yb = y_hist + ((size_t)(b0+col)*L_ + t)*OUT_;
      float yt[OUT_];
      #pragma unroll
      for (int o2=0;o2<OUT_;++o2){
        float4 s4 = *(const float4*)&yred[o2][col][0];
        float v = s4.x + s4.y + s4.z + s4.w + fc_b[o2];
        #pragma unroll
        for (int j=0;j<OUT_;++j) v += yb[j]*fc_w[o2*69 + 64 + j];
        yt[o2] = v;
      }
      ycv.u[0] = pack_rtn(yt[0], yt[1]);
      ycv.u[1] = pack_rtn(yt[2], yt[3]);
      ycv.u[2] = pack_rtn(yt[4], 0.f);
    }
    // gates = bias + y_tilde@Wih^T + h@Whh^T
    f32x4 accQ[4];
    #pragma unroll
    for (int q=0;q<4;++q){
      accQ[q][0]=((const float*)&bD[0])[q];
      accQ[q][1]=((const float*)&bD[1])[q];
      accQ[q][2]=((const float*)&bD[2])[q];
      accQ[q][3]=((const float*)&bD[3])[q];
    }
    #pragma unroll
    for (int q=0;q<4;++q){
      accQ[q] = __builtin_amdgcn_mfma_f32_16x16x32_f16(aG0[q], ycv.v, accQ[q], 0,0,0);
      accQ[q] = __builtin_amdgcn_mfma_f32_16x16x32_f16(aGh[q][0], hB[0], accQ[q], 0,0,0);
      accQ[q] = __builtin_amdgcn_mfma_f32_16x16x32_f16(aGh[q][1], hB[1], accQ[q], 0,0,0);
    }
    #pragma unroll
    for (int r=0;r<4;++r){
      float ig=sigmf(accQ[0][r]), fg=sigmf(accQ[1][r]), gg=tanhf_(accQ[2][r]), og=sigmf(accQ[3][r]);
      c[r]=fg*c[r]+ig*gg;
      h[r]=og*tanhf_(c[r]);
    }
    *(uint2*)&hxD[p^1][col][u0>>1] = make_uint2(pack_rtz(h[0],h[1]), pack_rtz(h[2],h[3]));
    *(uint2*)&cxD[p^1][col][u0>>1] = make_uint2(pack_rtz(c[0],c[1]), pack_rtz(c[2],c[3]));
    __syncthreads();
    p ^= 1;
  }

  // ---------------- epilogue: out = concat(h, ctx) @ fcout^T + b ----------------
  float op_[OUT_];
  #pragma unroll
  for (int o2=0;o2<OUT_;++o2){
    float pv = 0.f;
    #pragma unroll
    for (int r=0;r<4;++r)
      pv += h[r]*fcout_w[o2*128 + u0 + r] + ctx[r]*fcout_w[o2*128 + 64 + u0 + r];
    pv += __shfl_xor(pv,16);
    pv += __shfl_xor(pv,32);
    op_[o2] = pv;
  }
  if (g==0){
    #pragma unroll
    for (int o2=0;o2<OUT_;++o2) sred[o2][col][w] = op_[o2];
  }
  __syncthreads();
  if (w==0 && g==0){
    #pragma unroll
    for (int o2=0;o2<OUT_;++o2){
      float4 s4 = *(const float4*)&sred[o2][col][0];
      out[(size_t)(b0+col)*OUT_ + o2] = s4.x + s4.y + s4.z + s4.w + fcout_b[o2];
    }
  }
}

extern "C" void kernel_launch(void* const* d_in, const int* in_sizes, int n_in,
                              void* d_out, int out_size, void* d_ws, size_t ws_size,
                              hipStream_t stream) {
  const float* x          = (const float*)d_in[0];
  const float* y_hist     = (const float*)d_in[1];
  const float* h0_enc     = (const float*)d_in[2];
  const float* c0_enc     = (const float*)d_in[3];
  const float* h0_dec     = (const float*)d_in[4];
  const float* c0_dec     = (const float*)d_in[5];
  const float* enc_attn_w = (const float*)d_in[6];
  const float* enc_Wih    = (const float*)d_in[8];
  const float* enc_Whh    = (const float*)d_in[9];
  const float* enc_bih    = (const float*)d_in[10];
  const float* enc_bhh    = (const float*)d_in[11];
  const float* dec_attn_w1= (const float*)d_in[12];
  const float* dec_attn_b1= (const float*)d_in[13];
  const float* dec_attn_w2= (const float*)d_in[14];
  const float* dec_Wih    = (const float*)d_in[16];
  const float* dec_Whh    = (const float*)d_in[17];
  const float* dec_bih    = (const float*)d_in[18];
  const float* dec_bhh    = (const float*)d_in[19];
  const float* fc_w       = (const float*)d_in[20];
  const float* fc_b       = (const float*)d_in[21];
  const float* fcout_w    = (const float*)d_in[22];
  const float* fcout_b    = (const float*)d_in[23];
  float* ws = (float*)d_ws;
  float* out = (float*)d_out;
  uint2* Gp = (uint2*)((uint*)d_ws + WS_G);

  hipLaunchKernelGGL(prep_kernel, dim3(128), dim3(256), 0, stream,
                     enc_Wih, enc_Whh, enc_bih, enc_bhh,
                     dec_Wih, dec_Whh, dec_bih, dec_bhh,
                     dec_attn_w1, ws);
  hipLaunchKernelGGL(gemmG_mfma, dim3(B_/16), dim3(256), 0, stream,
                     x, enc_attn_w, ws, (_Float16*)Gp);
  hipLaunchKernelGGL(darnn_kernel, dim3(B_/16), dim3(256), 0, stream,
                     y_hist, h0_enc, c0_enc, h0_dec, c0_dec,
                     dec_attn_b1, dec_attn_w2,
                     fc_w, fc_b, fcout_w, fcout_b, ws, Gp, out);
}